// Round 1
// baseline (1147.128 us; speedup 1.0000x reference)
//
#include <hip/hip_runtime.h>
#include <hip/hip_bf16.h>

#define N_NODES 100000
#define D 128          // D_IN == D_OUT == 128

// ---------------------------------------------------------------------------
// Phase 1: scatter-add  h[dst[e]] += x[src[e]] * ew[e]
// 32 lanes per edge, float4 per lane -> one coalesced 512B row read per edge.
// ---------------------------------------------------------------------------
__global__ __launch_bounds__(256) void scatter_kernel(
    const float* __restrict__ x,
    const float* __restrict__ ew,
    const int*   __restrict__ src,
    const int*   __restrict__ dst,
    float*       __restrict__ h,
    int E)
{
    int t    = blockIdx.x * 256 + threadIdx.x;
    int e    = t >> 5;          // 32 threads per edge
    int lane = t & 31;
    if (e >= E) return;

    float w = ew[e];
    int   s = src[e];
    int   d = dst[e];

    float4 v = *reinterpret_cast<const float4*>(&x[(size_t)s * D + lane * 4]);
    float* hp = &h[(size_t)d * D + lane * 4];
    atomicAdd(hp + 0, v.x * w);
    atomicAdd(hp + 1, v.y * w);
    atomicAdd(hp + 2, v.z * w);
    atomicAdd(hp + 3, v.w * w);
}

// ---------------------------------------------------------------------------
// Phase 2: out = h @ W^T + b     (M=100000, N=128, K=128, fp32 vector ALU)
// Block tile 128x128, thread tile 8x8 (256 threads), K chunked by 32.
// LDS layout is [k][m] / [k][n] so fragment reads are contiguous float4s.
// ---------------------------------------------------------------------------
#define BM 128
#define BN 128
#define KC 32
#define TM 8
#define TN 8

__global__ __launch_bounds__(256) void gemm_kernel(
    const float* __restrict__ h,
    const float* __restrict__ W,
    const float* __restrict__ bias,
    float*       __restrict__ out,
    int M)
{
    __shared__ float hs[KC][BM + 4];   // [k][m], pad keeps rows 16B-aligned (132*4=528)
    __shared__ float ws[KC][BN + 4];   // [k][n]

    const int tid  = threadIdx.x;
    const int cg   = tid & 15;    // 16 col groups * TN=8  -> 128 cols
    const int rg   = tid >> 4;    // 16 row groups * TM=8  -> 128 rows
    const int row0 = blockIdx.x * BM;

    float acc[TM][TN] = {};

    for (int kc = 0; kc < D; kc += KC) {
        // stage h tile: 128 rows x 32 k = 1024 float4, 4 per thread
        #pragma unroll
        for (int i = 0; i < 4; ++i) {
            int f  = tid + i * 256;
            int r  = f >> 3;       // 8 float4 per row
            int c4 = f & 7;
            int row = row0 + r;
            float4 v = make_float4(0.f, 0.f, 0.f, 0.f);
            if (row < M)
                v = *reinterpret_cast<const float4*>(&h[(size_t)row * D + kc + c4 * 4]);
            hs[c4 * 4 + 0][r] = v.x;
            hs[c4 * 4 + 1][r] = v.y;
            hs[c4 * 4 + 2][r] = v.z;
            hs[c4 * 4 + 3][r] = v.w;
        }
        // stage W tile: 128 n-rows x 32 k
        #pragma unroll
        for (int i = 0; i < 4; ++i) {
            int f  = tid + i * 256;
            int n  = f >> 3;
            int c4 = f & 7;
            float4 v = *reinterpret_cast<const float4*>(&W[(size_t)n * D + kc + c4 * 4]);
            ws[c4 * 4 + 0][n] = v.x;
            ws[c4 * 4 + 1][n] = v.y;
            ws[c4 * 4 + 2][n] = v.z;
            ws[c4 * 4 + 3][n] = v.w;
        }
        __syncthreads();

        #pragma unroll
        for (int k = 0; k < KC; ++k) {
            float a[TM], w[TN];
            #pragma unroll
            for (int i = 0; i < TM; ++i) a[i] = hs[k][rg * TM + i];
            #pragma unroll
            for (int j = 0; j < TN; ++j) w[j] = ws[k][cg * TN + j];
            #pragma unroll
            for (int i = 0; i < TM; ++i)
                #pragma unroll
                for (int j = 0; j < TN; ++j)
                    acc[i][j] += a[i] * w[j];
        }
        __syncthreads();
    }

    // epilogue: add bias, coalesced float4 stores
    #pragma unroll
    for (int i = 0; i < TM; ++i) {
        int row = row0 + rg * TM + i;
        if (row >= M) continue;
        #pragma unroll
        for (int j4 = 0; j4 < TN / 4; ++j4) {
            int n = cg * TN + j4 * 4;
            float4 bv = *reinterpret_cast<const float4*>(&bias[n]);
            float4 o;
            o.x = acc[i][j4 * 4 + 0] + bv.x;
            o.y = acc[i][j4 * 4 + 1] + bv.y;
            o.z = acc[i][j4 * 4 + 2] + bv.z;
            o.w = acc[i][j4 * 4 + 3] + bv.w;
            *reinterpret_cast<float4*>(&out[(size_t)row * D + n]) = o;
        }
    }
}

extern "C" void kernel_launch(void* const* d_in, const int* in_sizes, int n_in,
                              void* d_out, int out_size, void* d_ws, size_t ws_size,
                              hipStream_t stream) {
    const float* x   = (const float*)d_in[0];
    const float* ew  = (const float*)d_in[1];
    const int*   src = (const int*)d_in[2];
    const int*   dst = (const int*)d_in[3];
    const float* W   = (const float*)d_in[4];
    const float* b   = (const float*)d_in[5];
    float*       out = (float*)d_out;
    float*       h   = (float*)d_ws;   // [N_NODES][D] fp32 accumulator, 51.2 MB

    const int E = in_sizes[2];               // 640000
    const int M = out_size / D;              // 100000

    // zero the segment-sum accumulator (workspace is poisoned, not re-zeroed)
    hipMemsetAsync(h, 0, (size_t)M * D * sizeof(float), stream);

    // scatter: 32 threads per edge
    {
        long long threads = (long long)E * 32;
        int blocks = (int)((threads + 255) / 256);
        scatter_kernel<<<blocks, 256, 0, stream>>>(x, ew, src, dst, h, E);
    }

    // dense: out = h @ W^T + b
    {
        int blocks = (M + BM - 1) / BM;
        gemm_kernel<<<blocks, 256, 0, stream>>>(h, W, b, out, M);
    }
}

// Round 2
// 327.058 us; speedup vs baseline: 3.5074x; 3.5074x over previous
//
#include <hip/hip_runtime.h>
#include <hip/hip_bf16.h>

#define D 128          // D_IN == D_OUT == 128

// ---------------------------------------------------------------------------
// CSR build: histogram of dst, exclusive scan, bin edges (packed {src, w}).
// ---------------------------------------------------------------------------
__global__ __launch_bounds__(256) void hist_kernel(
    const int* __restrict__ dst, int* __restrict__ cnt, int E)
{
    int e = blockIdx.x * 256 + threadIdx.x;
    if (e < E) atomicAdd(&cnt[dst[e]], 1);
}

// single-block exclusive scan over N counters -> base[0..N], cursor copy
__global__ __launch_bounds__(256) void scan_kernel(
    const int* __restrict__ cnt, int* __restrict__ base,
    int* __restrict__ cursor, int N, int E)
{
    __shared__ int wsum[4];
    __shared__ int carry_s;
    const int tid  = threadIdx.x;
    const int lane = tid & 63;
    const int wid  = tid >> 6;
    const int CH   = 256 * 16;
    const int nch  = (N + CH - 1) / CH;
    int carry = 0;

    for (int c = 0; c < nch; ++c) {
        int off = c * CH + tid * 16;
        int v[16];
        int s = 0;
        #pragma unroll
        for (int i = 0; i < 16; ++i) {
            int idx = off + i;
            v[i] = (idx < N) ? cnt[idx] : 0;
            s += v[i];
        }
        // inclusive wave scan of per-thread sums
        int ssum = s;
        #pragma unroll
        for (int d = 1; d < 64; d <<= 1) {
            int t = __shfl_up(ssum, d, 64);
            if (lane >= d) ssum += t;
        }
        if (lane == 63) wsum[wid] = ssum;
        __syncthreads();
        int woff = 0;
        for (int w = 0; w < wid; ++w) woff += wsum[w];
        int run = carry + woff + ssum - s;   // exclusive prefix of first elem
        #pragma unroll
        for (int i = 0; i < 16; ++i) {
            int idx = off + i;
            if (idx < N) { base[idx] = run; cursor[idx] = run; }
            run += v[i];
        }
        __syncthreads();
        if (tid == 0) {
            int tot = 0;
            for (int i = 0; i < 4; ++i) tot += wsum[i];
            carry_s = carry + tot;
        }
        __syncthreads();
        carry = carry_s;
    }
    if (tid == 0) base[N] = E;
}

__global__ __launch_bounds__(256) void bin_kernel(
    const int* __restrict__ src, const int* __restrict__ dst,
    const float* __restrict__ ew, int* __restrict__ cursor,
    int2* __restrict__ bins, int E)
{
    int e = blockIdx.x * 256 + threadIdx.x;
    if (e >= E) return;
    int p = atomicAdd(&cursor[dst[e]], 1);
    bins[p] = make_int2(src[e], __float_as_int(ew[e]));
}

// ---------------------------------------------------------------------------
// Gather-sum: one wave per node.  out[n] = sum_e y[src_e]*w_e + bias
// ---------------------------------------------------------------------------
__global__ __launch_bounds__(256) void gather_kernel(
    const float* __restrict__ y, const int* __restrict__ base,
    const int2* __restrict__ bins, const float* __restrict__ bias,
    float* __restrict__ out, int N)
{
    int gw   = (blockIdx.x * 256 + threadIdx.x) >> 6;
    int lane = threadIdx.x & 63;
    if (gw >= N) return;

    int b0 = base[gw], b1 = base[gw + 1];
    float2 acc = make_float2(0.f, 0.f);

    int i = b0;
    for (; i + 1 < b1; i += 2) {           // 2x unroll: two gathers in flight
        int2 e0 = bins[i], e1 = bins[i + 1];
        float w0 = __int_as_float(e0.y), w1 = __int_as_float(e1.y);
        float2 v0 = *reinterpret_cast<const float2*>(&y[(size_t)e0.x * D + lane * 2]);
        float2 v1 = *reinterpret_cast<const float2*>(&y[(size_t)e1.x * D + lane * 2]);
        acc.x += v0.x * w0; acc.y += v0.y * w0;
        acc.x += v1.x * w1; acc.y += v1.y * w1;
    }
    if (i < b1) {
        int2 e0 = bins[i];
        float w0 = __int_as_float(e0.y);
        float2 v0 = *reinterpret_cast<const float2*>(&y[(size_t)e0.x * D + lane * 2]);
        acc.x += v0.x * w0; acc.y += v0.y * w0;
    }

    float2 bv = *reinterpret_cast<const float2*>(&bias[lane * 2]);
    acc.x += bv.x; acc.y += bv.y;
    *reinterpret_cast<float2*>(&out[(size_t)gw * D + lane * 2]) = acc;
}

// ---------------------------------------------------------------------------
// GEMM: out = in @ W^T (+ bias if non-null).  M x 128 x 128 fp32.
// Block tile 128x128, thread tile 8x8, K chunked by 32, [k][m]/[k][n] LDS.
// ---------------------------------------------------------------------------
#define BM 128
#define BN 128
#define KC 32
#define TM 8
#define TN 8

__global__ __launch_bounds__(256) void gemm_kernel(
    const float* __restrict__ h,
    const float* __restrict__ W,
    const float* __restrict__ bias,   // nullable
    float*       __restrict__ out,
    int M)
{
    __shared__ float hs[KC][BM + 4];
    __shared__ float ws[KC][BN + 4];

    const int tid  = threadIdx.x;
    const int cg   = tid & 15;
    const int rg   = tid >> 4;
    const int row0 = blockIdx.x * BM;

    float acc[TM][TN] = {};

    for (int kc = 0; kc < D; kc += KC) {
        #pragma unroll
        for (int i = 0; i < 4; ++i) {
            int f  = tid + i * 256;
            int r  = f >> 3;
            int c4 = f & 7;
            int row = row0 + r;
            float4 v = make_float4(0.f, 0.f, 0.f, 0.f);
            if (row < M)
                v = *reinterpret_cast<const float4*>(&h[(size_t)row * D + kc + c4 * 4]);
            hs[c4 * 4 + 0][r] = v.x;
            hs[c4 * 4 + 1][r] = v.y;
            hs[c4 * 4 + 2][r] = v.z;
            hs[c4 * 4 + 3][r] = v.w;
        }
        #pragma unroll
        for (int i = 0; i < 4; ++i) {
            int f  = tid + i * 256;
            int n  = f >> 3;
            int c4 = f & 7;
            float4 v = *reinterpret_cast<const float4*>(&W[(size_t)n * D + kc + c4 * 4]);
            ws[c4 * 4 + 0][n] = v.x;
            ws[c4 * 4 + 1][n] = v.y;
            ws[c4 * 4 + 2][n] = v.z;
            ws[c4 * 4 + 3][n] = v.w;
        }
        __syncthreads();

        #pragma unroll
        for (int k = 0; k < KC; ++k) {
            float a[TM], w[TN];
            #pragma unroll
            for (int i = 0; i < TM; ++i) a[i] = hs[k][rg * TM + i];
            #pragma unroll
            for (int j = 0; j < TN; ++j) w[j] = ws[k][cg * TN + j];
            #pragma unroll
            for (int i = 0; i < TM; ++i)
                #pragma unroll
                for (int j = 0; j < TN; ++j)
                    acc[i][j] += a[i] * w[j];
        }
        __syncthreads();
    }

    #pragma unroll
    for (int i = 0; i < TM; ++i) {
        int row = row0 + rg * TM + i;
        if (row >= M) continue;
        #pragma unroll
        for (int j4 = 0; j4 < TN / 4; ++j4) {
            int n = cg * TN + j4 * 4;
            float4 bv = make_float4(0.f, 0.f, 0.f, 0.f);
            if (bias) bv = *reinterpret_cast<const float4*>(&bias[n]);
            float4 o;
            o.x = acc[i][j4 * 4 + 0] + bv.x;
            o.y = acc[i][j4 * 4 + 1] + bv.y;
            o.z = acc[i][j4 * 4 + 2] + bv.z;
            o.w = acc[i][j4 * 4 + 3] + bv.w;
            *reinterpret_cast<float4*>(&out[(size_t)row * D + n]) = o;
        }
    }
}

// ---------------------------------------------------------------------------
// Fallback (ws too small): original atomic scatter into h, then GEMM+bias.
// ---------------------------------------------------------------------------
__global__ __launch_bounds__(256) void scatter_kernel(
    const float* __restrict__ x,
    const float* __restrict__ ew,
    const int*   __restrict__ src,
    const int*   __restrict__ dst,
    float*       __restrict__ h,
    int E)
{
    int t    = blockIdx.x * 256 + threadIdx.x;
    int e    = t >> 5;
    int lane = t & 31;
    if (e >= E) return;
    float w = ew[e];
    int   s = src[e];
    int   d = dst[e];
    float4 v = *reinterpret_cast<const float4*>(&x[(size_t)s * D + lane * 4]);
    float* hp = &h[(size_t)d * D + lane * 4];
    atomicAdd(hp + 0, v.x * w);
    atomicAdd(hp + 1, v.y * w);
    atomicAdd(hp + 2, v.z * w);
    atomicAdd(hp + 3, v.w * w);
}

extern "C" void kernel_launch(void* const* d_in, const int* in_sizes, int n_in,
                              void* d_out, int out_size, void* d_ws, size_t ws_size,
                              hipStream_t stream) {
    const float* x   = (const float*)d_in[0];
    const float* ew  = (const float*)d_in[1];
    const int*   src = (const int*)d_in[2];
    const int*   dst = (const int*)d_in[3];
    const float* W   = (const float*)d_in[4];
    const float* b   = (const float*)d_in[5];
    float*       out = (float*)d_out;

    const int E = in_sizes[2];          // 640000
    const int M = out_size / D;         // 100000 nodes

    // ws layout: y[M*D] f32 | bins[E] int2 | base[M+1] | cnt[M] | cursor[M]
    size_t need = (size_t)M * D * 4 + (size_t)E * 8 + (size_t)(3 * M + 1) * 4;

    if (ws_size >= need) {
        float* y      = (float*)d_ws;
        int2*  bins   = (int2*)(y + (size_t)M * D);
        int*   base   = (int*)(bins + E);
        int*   cnt    = base + (M + 1);
        int*   cursor = cnt + M;

        hipMemsetAsync(cnt, 0, (size_t)M * sizeof(int), stream);

        // y = x @ W^T   (linearity: segment_sum then linear == linear then segment_sum)
        gemm_kernel<<<(M + BM - 1) / BM, 256, 0, stream>>>(x, W, nullptr, y, M);

        // CSR build
        hist_kernel<<<(E + 255) / 256, 256, 0, stream>>>(dst, cnt, E);
        scan_kernel<<<1, 256, 0, stream>>>(cnt, base, cursor, M, E);
        bin_kernel<<<(E + 255) / 256, 256, 0, stream>>>(src, dst, ew, cursor, bins, E);

        // out[n] = sum_{e in node n} y[src_e] * w_e + bias
        int waves  = M;
        int blocks = (waves * 64 + 255) / 256;
        gather_kernel<<<blocks, 256, 0, stream>>>(y, base, bins, b, out, M);
    } else {
        // fallback: atomic scatter + GEMM
        float* h = (float*)d_ws;
        hipMemsetAsync(h, 0, (size_t)M * D * sizeof(float), stream);
        long long threads = (long long)E * 32;
        scatter_kernel<<<(int)((threads + 255) / 256), 256, 0, stream>>>(x, ew, src, dst, h, E);
        gemm_kernel<<<(M + BM - 1) / BM, 256, 0, stream>>>(h, W, b, out, M);
    }
}

// Round 3
// 200.591 us; speedup vs baseline: 5.7187x; 1.6305x over previous
//
#include <hip/hip_runtime.h>
#include <hip/hip_bf16.h>

#define D 128          // D_IN == D_OUT == 128
#define SCAN_CH 4096   // elements per scan block (256 threads x 16)

// ---------------------------------------------------------------------------
// CSR build: histogram of dst, multi-block exclusive scan, bin edges.
// ---------------------------------------------------------------------------
__global__ __launch_bounds__(256) void hist_kernel(
    const int* __restrict__ dst, int* __restrict__ cnt, int E)
{
    int e = blockIdx.x * 256 + threadIdx.x;
    if (e < E) atomicAdd(&cnt[dst[e]], 1);
}

// pass 1: per-block chunk sums
__global__ __launch_bounds__(256) void scan_part_kernel(
    const int* __restrict__ cnt, int* __restrict__ bsum, int N)
{
    __shared__ int wred[4];
    const int tid  = threadIdx.x;
    const int lane = tid & 63;
    const int wid  = tid >> 6;
    int off = blockIdx.x * SCAN_CH + tid * 16;
    int s = 0;
    #pragma unroll
    for (int i = 0; i < 16; ++i) {
        int idx = off + i;
        if (idx < N) s += cnt[idx];
    }
    #pragma unroll
    for (int d = 32; d >= 1; d >>= 1) s += __shfl_xor(s, d, 64);
    if (lane == 0) wred[wid] = s;
    __syncthreads();
    if (tid == 0) bsum[blockIdx.x] = wred[0] + wred[1] + wred[2] + wred[3];
}

// pass 2: each block sums preceding bsums (NB <= 64, one wave) then scans its
// chunk and writes base + cursor.
__global__ __launch_bounds__(256) void scan_write_kernel(
    const int* __restrict__ cnt, const int* __restrict__ bsum,
    int* __restrict__ base, int* __restrict__ cursor, int N, int E, int NB)
{
    __shared__ int boff_s;
    __shared__ int wsum[4];
    const int b    = blockIdx.x;
    const int tid  = threadIdx.x;
    const int lane = tid & 63;
    const int wid  = tid >> 6;

    if (wid == 0) {
        int v = (lane < b) ? bsum[lane] : 0;   // NB <= 64 guaranteed
        #pragma unroll
        for (int d = 32; d >= 1; d >>= 1) v += __shfl_xor(v, d, 64);
        if (lane == 0) boff_s = v;
    }
    __syncthreads();

    int off = b * SCAN_CH + tid * 16;
    int v[16];
    int s = 0;
    #pragma unroll
    for (int i = 0; i < 16; ++i) {
        int idx = off + i;
        v[i] = (idx < N) ? cnt[idx] : 0;
        s += v[i];
    }
    int ssum = s;                               // inclusive wave scan
    #pragma unroll
    for (int d = 1; d < 64; d <<= 1) {
        int t = __shfl_up(ssum, d, 64);
        if (lane >= d) ssum += t;
    }
    if (lane == 63) wsum[wid] = ssum;
    __syncthreads();
    int woff = 0;
    for (int w = 0; w < wid; ++w) woff += wsum[w];

    int run = boff_s + woff + ssum - s;         // exclusive prefix of v[0]
    #pragma unroll
    for (int i = 0; i < 16; ++i) {
        int idx = off + i;
        if (idx < N) { base[idx] = run; cursor[idx] = run; }
        run += v[i];
    }
    if (b == 0 && tid == 0) base[N] = E;
}

__global__ __launch_bounds__(256) void bin_kernel(
    const int* __restrict__ src, const int* __restrict__ dst,
    const float* __restrict__ ew, int* __restrict__ cursor,
    int2* __restrict__ bins, int E)
{
    int e = blockIdx.x * 256 + threadIdx.x;
    if (e >= E) return;
    int p = atomicAdd(&cursor[dst[e]], 1);
    bins[p] = make_int2(src[e], __float_as_int(ew[e]));
}

// ---------------------------------------------------------------------------
// Gather-sum: one wave per node.  out[n] = sum_e y[src_e]*w_e + bias
// ---------------------------------------------------------------------------
__global__ __launch_bounds__(256) void gather_kernel(
    const float* __restrict__ y, const int* __restrict__ base,
    const int2* __restrict__ bins, const float* __restrict__ bias,
    float* __restrict__ out, int N)
{
    int gw   = (blockIdx.x * 256 + threadIdx.x) >> 6;
    int lane = threadIdx.x & 63;
    if (gw >= N) return;

    int b0 = base[gw], b1 = base[gw + 1];
    float2 acc = make_float2(0.f, 0.f);

    int i = b0;
    for (; i + 1 < b1; i += 2) {
        int2 e0 = bins[i], e1 = bins[i + 1];
        float w0 = __int_as_float(e0.y), w1 = __int_as_float(e1.y);
        float2 v0 = *reinterpret_cast<const float2*>(&y[(size_t)e0.x * D + lane * 2]);
        float2 v1 = *reinterpret_cast<const float2*>(&y[(size_t)e1.x * D + lane * 2]);
        acc.x += v0.x * w0; acc.y += v0.y * w0;
        acc.x += v1.x * w1; acc.y += v1.y * w1;
    }
    if (i < b1) {
        int2 e0 = bins[i];
        float w0 = __int_as_float(e0.y);
        float2 v0 = *reinterpret_cast<const float2*>(&y[(size_t)e0.x * D + lane * 2]);
        acc.x += v0.x * w0; acc.y += v0.y * w0;
    }

    float2 bv = *reinterpret_cast<const float2*>(&bias[lane * 2]);
    acc.x += bv.x; acc.y += bv.y;
    *reinterpret_cast<float2*>(&out[(size_t)gw * D + lane * 2]) = acc;
}

// ---------------------------------------------------------------------------
// GEMM: out = in @ W^T (+ bias if non-null).  M x 128 x 128 fp32.
// ---------------------------------------------------------------------------
#define BM 128
#define BN 128
#define KC 32
#define TM 8
#define TN 8

__global__ __launch_bounds__(256) void gemm_kernel(
    const float* __restrict__ h,
    const float* __restrict__ W,
    const float* __restrict__ bias,   // nullable
    float*       __restrict__ out,
    int M)
{
    __shared__ float hs[KC][BM + 4];
    __shared__ float ws[KC][BN + 4];

    const int tid  = threadIdx.x;
    const int cg   = tid & 15;
    const int rg   = tid >> 4;
    const int row0 = blockIdx.x * BM;

    float acc[TM][TN] = {};

    for (int kc = 0; kc < D; kc += KC) {
        #pragma unroll
        for (int i = 0; i < 4; ++i) {
            int f  = tid + i * 256;
            int r  = f >> 3;
            int c4 = f & 7;
            int row = row0 + r;
            float4 v = make_float4(0.f, 0.f, 0.f, 0.f);
            if (row < M)
                v = *reinterpret_cast<const float4*>(&h[(size_t)row * D + kc + c4 * 4]);
            hs[c4 * 4 + 0][r] = v.x;
            hs[c4 * 4 + 1][r] = v.y;
            hs[c4 * 4 + 2][r] = v.z;
            hs[c4 * 4 + 3][r] = v.w;
        }
        #pragma unroll
        for (int i = 0; i < 4; ++i) {
            int f  = tid + i * 256;
            int n  = f >> 3;
            int c4 = f & 7;
            float4 v = *reinterpret_cast<const float4*>(&W[(size_t)n * D + kc + c4 * 4]);
            ws[c4 * 4 + 0][n] = v.x;
            ws[c4 * 4 + 1][n] = v.y;
            ws[c4 * 4 + 2][n] = v.z;
            ws[c4 * 4 + 3][n] = v.w;
        }
        __syncthreads();

        #pragma unroll
        for (int k = 0; k < KC; ++k) {
            float a[TM], w[TN];
            #pragma unroll
            for (int i = 0; i < TM; ++i) a[i] = hs[k][rg * TM + i];
            #pragma unroll
            for (int j = 0; j < TN; ++j) w[j] = ws[k][cg * TN + j];
            #pragma unroll
            for (int i = 0; i < TM; ++i)
                #pragma unroll
                for (int j = 0; j < TN; ++j)
                    acc[i][j] += a[i] * w[j];
        }
        __syncthreads();
    }

    #pragma unroll
    for (int i = 0; i < TM; ++i) {
        int row = row0 + rg * TM + i;
        if (row >= M) continue;
        #pragma unroll
        for (int j4 = 0; j4 < TN / 4; ++j4) {
            int n = cg * TN + j4 * 4;
            float4 bv = make_float4(0.f, 0.f, 0.f, 0.f);
            if (bias) bv = *reinterpret_cast<const float4*>(&bias[n]);
            float4 o;
            o.x = acc[i][j4 * 4 + 0] + bv.x;
            o.y = acc[i][j4 * 4 + 1] + bv.y;
            o.z = acc[i][j4 * 4 + 2] + bv.z;
            o.w = acc[i][j4 * 4 + 3] + bv.w;
            *reinterpret_cast<float4*>(&out[(size_t)row * D + n]) = o;
        }
    }
}

extern "C" void kernel_launch(void* const* d_in, const int* in_sizes, int n_in,
                              void* d_out, int out_size, void* d_ws, size_t ws_size,
                              hipStream_t stream) {
    const float* x   = (const float*)d_in[0];
    const float* ew  = (const float*)d_in[1];
    const int*   src = (const int*)d_in[2];
    const int*   dst = (const int*)d_in[3];
    const float* W   = (const float*)d_in[4];
    const float* b   = (const float*)d_in[5];
    float*       out = (float*)d_out;

    const int E = in_sizes[2];          // 640000
    const int M = out_size / D;         // 100000 nodes
    const int NB = (M + SCAN_CH - 1) / SCAN_CH;   // 25 blocks (<=64 required)

    // ws layout: y[M*D] f32 | bins[E] int2 | base[M+1] | cnt[M] | cursor[M] | bsum[NB]
    float* y      = (float*)d_ws;
    int2*  bins   = (int2*)(y + (size_t)M * D);
    int*   base   = (int*)(bins + E);
    int*   cnt    = base + (M + 1);
    int*   cursor = cnt + M;
    int*   bsum   = cursor + M;

    hipMemsetAsync(cnt, 0, (size_t)M * sizeof(int), stream);

    // y = x @ W^T   (linearity: linear commutes with segment_sum)
    gemm_kernel<<<(M + BM - 1) / BM, 256, 0, stream>>>(x, W, nullptr, y, M);

    // CSR build
    hist_kernel<<<(E + 255) / 256, 256, 0, stream>>>(dst, cnt, E);
    scan_part_kernel<<<NB, 256, 0, stream>>>(cnt, bsum, M);
    scan_write_kernel<<<NB, 256, 0, stream>>>(cnt, bsum, base, cursor, M, E, NB);
    bin_kernel<<<(E + 255) / 256, 256, 0, stream>>>(src, dst, ew, cursor, bins, E);

    // out[n] = sum_{e in node n} y[src_e] * w_e + bias
    int blocks = (M * 64 + 255) / 256;
    gather_kernel<<<blocks, 256, 0, stream>>>(y, base, bins, b, out, M);
}

// Round 4
// 163.321 us; speedup vs baseline: 7.0238x; 1.2282x over previous
//
#include <hip/hip_runtime.h>
#include <hip/hip_bf16.h>

#define D 128          // D_IN == D_OUT == 128
#define SCAN_CH 4096   // elements per scan block (256 threads x 16)

typedef __bf16 bf16x8 __attribute__((ext_vector_type(8)));
typedef float  f32x4  __attribute__((ext_vector_type(4)));

__device__ __forceinline__ __bf16 f2bf(float f) { return (__bf16)f; }

// ---------------------------------------------------------------------------
// Pack W (fp32 [n][k] row-major) into MFMA B-fragment order, bf16.
// Fragment (kb, fn), lane l holds B[k=kb*32+(l>>4)*8+j][n=fn*16+(l&15)]
//                              = W[fn*16+(l&15)][kb*32+(l>>4)*8+j], j=0..7.
// Flat layout: wb[((kb*8+fn)*64 + lane)*8 + j]
// ---------------------------------------------------------------------------
__global__ __launch_bounds__(256) void pack_w_kernel(
    const float* __restrict__ W, __bf16* __restrict__ wb)
{
    int t    = blockIdx.x * 256 + threadIdx.x;   // 0..2047
    int lane = t & 63;
    int frag = t >> 6;                           // 0..31 = kb*8+fn
    int kb = frag >> 3, fn = frag & 7;
    int n  = fn * 16 + (lane & 15);
    int k0 = kb * 32 + (lane >> 4) * 8;
    const float* src = &W[(size_t)n * D + k0];
    float4 v0 = *reinterpret_cast<const float4*>(src);
    float4 v1 = *reinterpret_cast<const float4*>(src + 4);
    bf16x8 o;
    o[0]=f2bf(v0.x); o[1]=f2bf(v0.y); o[2]=f2bf(v0.z); o[3]=f2bf(v0.w);
    o[4]=f2bf(v1.x); o[5]=f2bf(v1.y); o[6]=f2bf(v1.z); o[7]=f2bf(v1.w);
    *reinterpret_cast<bf16x8*>(&wb[((size_t)frag * 64 + lane) * 8]) = o;
}

// ---------------------------------------------------------------------------
// y = x @ W^T  via bf16 MFMA, output bf16.  No LDS; A frags converted inline.
// Block = 256 thr = 4 waves; wave owns 32 rows x 128 cols (2x8 frags, kb 0..3).
// ---------------------------------------------------------------------------
__global__ __launch_bounds__(256) void gemm_mfma_kernel(
    const float* __restrict__ x, const __bf16* __restrict__ wb,
    __bf16* __restrict__ y, int M)
{
    const int tid  = threadIdx.x;
    const int lane = tid & 63;
    const int wv   = tid >> 6;
    const int l15  = lane & 15;
    const int l4   = lane >> 4;
    const int row_base = blockIdx.x * 128 + wv * 32;

    f32x4 acc[2][8];
    #pragma unroll
    for (int mi = 0; mi < 2; ++mi)
        #pragma unroll
        for (int fn = 0; fn < 8; ++fn)
            #pragma unroll
            for (int c = 0; c < 4; ++c) acc[mi][fn][c] = 0.f;

    #pragma unroll
    for (int kb = 0; kb < 4; ++kb) {
        bf16x8 b[8];
        #pragma unroll
        for (int fn = 0; fn < 8; ++fn)
            b[fn] = *reinterpret_cast<const bf16x8*>(
                        &wb[((size_t)(kb * 8 + fn) * 64 + lane) * 8]);
        #pragma unroll
        for (int mi = 0; mi < 2; ++mi) {
            int row = row_base + mi * 16 + l15;
            int rc  = row < M ? row : M - 1;        // clamp; stores guarded
            const float* ap = &x[(size_t)rc * D + kb * 32 + l4 * 8];
            float4 v0 = *reinterpret_cast<const float4*>(ap);
            float4 v1 = *reinterpret_cast<const float4*>(ap + 4);
            bf16x8 a;
            a[0]=f2bf(v0.x); a[1]=f2bf(v0.y); a[2]=f2bf(v0.z); a[3]=f2bf(v0.w);
            a[4]=f2bf(v1.x); a[5]=f2bf(v1.y); a[6]=f2bf(v1.z); a[7]=f2bf(v1.w);
            #pragma unroll
            for (int fn = 0; fn < 8; ++fn)
                acc[mi][fn] = __builtin_amdgcn_mfma_f32_16x16x32_bf16(
                                  a, b[fn], acc[mi][fn], 0, 0, 0);
        }
    }

    // C/D layout: col = lane&15 (+fn*16), row = (lane>>4)*4 + r (+mi*16)
    #pragma unroll
    for (int mi = 0; mi < 2; ++mi)
        #pragma unroll
        for (int r = 0; r < 4; ++r) {
            int row = row_base + mi * 16 + l4 * 4 + r;
            if (row >= M) continue;
            #pragma unroll
            for (int fn = 0; fn < 8; ++fn)
                y[(size_t)row * D + fn * 16 + l15] = f2bf(acc[mi][fn][r]);
        }
}

// ---------------------------------------------------------------------------
// CSR build: histogram of dst, multi-block exclusive scan, bin edges.
// ---------------------------------------------------------------------------
__global__ __launch_bounds__(256) void hist_kernel(
    const int* __restrict__ dst, int* __restrict__ cnt, int E)
{
    int e = blockIdx.x * 256 + threadIdx.x;
    if (e < E) atomicAdd(&cnt[dst[e]], 1);
}

__global__ __launch_bounds__(256) void scan_part_kernel(
    const int* __restrict__ cnt, int* __restrict__ bsum, int N)
{
    __shared__ int wred[4];
    const int tid  = threadIdx.x;
    const int lane = tid & 63;
    const int wid  = tid >> 6;
    int off = blockIdx.x * SCAN_CH + tid * 16;
    int s = 0;
    #pragma unroll
    for (int i = 0; i < 16; ++i) {
        int idx = off + i;
        if (idx < N) s += cnt[idx];
    }
    #pragma unroll
    for (int d = 32; d >= 1; d >>= 1) s += __shfl_xor(s, d, 64);
    if (lane == 0) wred[wid] = s;
    __syncthreads();
    if (tid == 0) bsum[blockIdx.x] = wred[0] + wred[1] + wred[2] + wred[3];
}

__global__ __launch_bounds__(256) void scan_write_kernel(
    const int* __restrict__ cnt, const int* __restrict__ bsum,
    int* __restrict__ base, int* __restrict__ cursor, int N, int E, int NB)
{
    __shared__ int boff_s;
    __shared__ int wsum[4];
    const int b    = blockIdx.x;
    const int tid  = threadIdx.x;
    const int lane = tid & 63;
    const int wid  = tid >> 6;

    if (wid == 0) {
        int v = (lane < b) ? bsum[lane] : 0;   // NB <= 64
        #pragma unroll
        for (int d = 32; d >= 1; d >>= 1) v += __shfl_xor(v, d, 64);
        if (lane == 0) boff_s = v;
    }
    __syncthreads();

    int off = b * SCAN_CH + tid * 16;
    int v[16];
    int s = 0;
    #pragma unroll
    for (int i = 0; i < 16; ++i) {
        int idx = off + i;
        v[i] = (idx < N) ? cnt[idx] : 0;
        s += v[i];
    }
    int ssum = s;
    #pragma unroll
    for (int d = 1; d < 64; d <<= 1) {
        int t = __shfl_up(ssum, d, 64);
        if (lane >= d) ssum += t;
    }
    if (lane == 63) wsum[wid] = ssum;
    __syncthreads();
    int woff = 0;
    for (int w = 0; w < wid; ++w) woff += wsum[w];

    int run = boff_s + woff + ssum - s;
    #pragma unroll
    for (int i = 0; i < 16; ++i) {
        int idx = off + i;
        if (idx < N) { base[idx] = run; cursor[idx] = run; }
        run += v[i];
    }
    if (b == 0 && tid == 0) base[N] = E;
}

__global__ __launch_bounds__(256) void bin_kernel(
    const int* __restrict__ src, const int* __restrict__ dst,
    const float* __restrict__ ew, int* __restrict__ cursor,
    int2* __restrict__ bins, int E)
{
    int e = blockIdx.x * 256 + threadIdx.x;
    if (e >= E) return;
    int p = atomicAdd(&cursor[dst[e]], 1);
    bins[p] = make_int2(src[e], __float_as_int(ew[e]));
}

// ---------------------------------------------------------------------------
// Gather-sum from bf16 y: one wave per node. out[n] = sum y[src]*w + bias.
// Each lane owns 2 adjacent cols -> one uint (2 bf16) per edge row.
// ---------------------------------------------------------------------------
__global__ __launch_bounds__(256) void gather_kernel(
    const __bf16* __restrict__ y, const int* __restrict__ base,
    const int2* __restrict__ bins, const float* __restrict__ bias,
    float* __restrict__ out, int N)
{
    int gw   = (blockIdx.x * 256 + threadIdx.x) >> 6;
    int lane = threadIdx.x & 63;
    if (gw >= N) return;

    const unsigned* yb = reinterpret_cast<const unsigned*>(y);  // 2 bf16 / uint
    int b0 = base[gw], b1 = base[gw + 1];
    float accx = 0.f, accy = 0.f;

    int i = b0;
    for (; i + 1 < b1; i += 2) {
        int2 e0 = bins[i], e1 = bins[i + 1];
        float w0 = __int_as_float(e0.y), w1 = __int_as_float(e1.y);
        unsigned p0 = yb[(size_t)e0.x * (D / 2) + lane];
        unsigned p1 = yb[(size_t)e1.x * (D / 2) + lane];
        accx += __uint_as_float(p0 << 16) * w0;
        accy += __uint_as_float(p0 & 0xFFFF0000u) * w0;
        accx += __uint_as_float(p1 << 16) * w1;
        accy += __uint_as_float(p1 & 0xFFFF0000u) * w1;
    }
    if (i < b1) {
        int2 e0 = bins[i];
        float w0 = __int_as_float(e0.y);
        unsigned p0 = yb[(size_t)e0.x * (D / 2) + lane];
        accx += __uint_as_float(p0 << 16) * w0;
        accy += __uint_as_float(p0 & 0xFFFF0000u) * w0;
    }

    float2 bv = *reinterpret_cast<const float2*>(&bias[lane * 2]);
    float2 o = make_float2(accx + bv.x, accy + bv.y);
    *reinterpret_cast<float2*>(&out[(size_t)gw * D + lane * 2]) = o;
}

extern "C" void kernel_launch(void* const* d_in, const int* in_sizes, int n_in,
                              void* d_out, int out_size, void* d_ws, size_t ws_size,
                              hipStream_t stream) {
    const float* x   = (const float*)d_in[0];
    const float* ew  = (const float*)d_in[1];
    const int*   src = (const int*)d_in[2];
    const int*   dst = (const int*)d_in[3];
    const float* W   = (const float*)d_in[4];
    const float* b   = (const float*)d_in[5];
    float*       out = (float*)d_out;

    const int E  = in_sizes[2];                 // 640000
    const int M  = out_size / D;                // 100000 nodes
    const int NB = (M + SCAN_CH - 1) / SCAN_CH; // 25 (<=64 required)

    // ws layout: y bf16[M*D] | wb bf16[32*64*8] | bins int2[E] | base[M+1] |
    //            cnt[M] | cursor[M] | bsum[NB]
    char* p = (char*)d_ws;
    __bf16* y    = (__bf16*)p;             p += (size_t)M * D * 2;
    __bf16* wb   = (__bf16*)p;             p += (size_t)32 * 64 * 8 * 2;
    int2*   bins = (int2*)p;               p += (size_t)E * 8;
    int*    base = (int*)p;                p += (size_t)(M + 1) * 4;
    int*    cnt  = (int*)p;                p += (size_t)M * 4;
    int*    cursor = (int*)p;              p += (size_t)M * 4;
    int*    bsum = (int*)p;

    hipMemsetAsync(cnt, 0, (size_t)M * sizeof(int), stream);

    // W -> fragment-ordered bf16
    pack_w_kernel<<<8, 256, 0, stream>>>(W, wb);

    // y = x @ W^T  (linear commutes with segment_sum)
    gemm_mfma_kernel<<<(M + 127) / 128, 256, 0, stream>>>(x, wb, y, M);

    // CSR build
    hist_kernel<<<(E + 255) / 256, 256, 0, stream>>>(dst, cnt, E);
    scan_part_kernel<<<NB, 256, 0, stream>>>(cnt, bsum, M);
    scan_write_kernel<<<NB, 256, 0, stream>>>(cnt, bsum, base, cursor, M, E, NB);
    bin_kernel<<<(E + 255) / 256, 256, 0, stream>>>(src, dst, ew, cursor, bins, E);

    // out[n] = sum_{e in node n} y[src_e] * w_e + bias
    gather_kernel<<<(M * 64 + 255) / 256, 256, 0, stream>>>(y, base, bins, b, out, M);
}

// Round 6
// 136.046 us; speedup vs baseline: 8.4319x; 1.2005x over previous
//
#include <hip/hip_runtime.h>
#include <hip/hip_bf16.h>

#define D 128          // D_IN == D_OUT == 128
#define SCAN_CH 4096   // elements per scan block (256 threads x 16)

typedef __bf16 bf16x8 __attribute__((ext_vector_type(8)));
typedef float  f32x4  __attribute__((ext_vector_type(4)));
typedef float  f32x2  __attribute__((ext_vector_type(2)));

__device__ __forceinline__ __bf16 f2bf(float f) { return (__bf16)f; }

// ---------------------------------------------------------------------------
// Pack W (fp32 [n][k] row-major) into MFMA B-fragment order, bf16.
// Fragment (kb, fn), lane l holds B[k=kb*32+(l>>4)*8+j][n=fn*16+(l&15)]
// Flat layout: wb[((kb*8+fn)*64 + lane)*8 + j]
// ---------------------------------------------------------------------------
__global__ __launch_bounds__(256) void pack_w_kernel(
    const float* __restrict__ W, __bf16* __restrict__ wb)
{
    int t    = blockIdx.x * 256 + threadIdx.x;   // 0..2047
    int lane = t & 63;
    int frag = t >> 6;                           // 0..31 = kb*8+fn
    int kb = frag >> 3, fn = frag & 7;
    int n  = fn * 16 + (lane & 15);
    int k0 = kb * 32 + (lane >> 4) * 8;
    const float* src = &W[(size_t)n * D + k0];
    float4 v0 = *reinterpret_cast<const float4*>(src);
    float4 v1 = *reinterpret_cast<const float4*>(src + 4);
    bf16x8 o;
    o[0]=f2bf(v0.x); o[1]=f2bf(v0.y); o[2]=f2bf(v0.z); o[3]=f2bf(v0.w);
    o[4]=f2bf(v1.x); o[5]=f2bf(v1.y); o[6]=f2bf(v1.z); o[7]=f2bf(v1.w);
    *reinterpret_cast<bf16x8*>(&wb[((size_t)frag * 64 + lane) * 8]) = o;
}

// ---------------------------------------------------------------------------
// y = x @ W^T  via bf16 MFMA, output bf16.  No LDS; A frags converted inline.
// Block = 256 thr = 4 waves; wave owns 32 rows x 128 cols (2x8 frags, kb 0..3).
// x loads are non-temporal (stream-once) to preserve L2 for y.
// ---------------------------------------------------------------------------
__global__ __launch_bounds__(256) void gemm_mfma_kernel(
    const float* __restrict__ x, const __bf16* __restrict__ wb,
    __bf16* __restrict__ y, int M)
{
    const int tid  = threadIdx.x;
    const int lane = tid & 63;
    const int wv   = tid >> 6;
    const int l15  = lane & 15;
    const int l4   = lane >> 4;
    const int row_base = blockIdx.x * 128 + wv * 32;

    f32x4 acc[2][8];
    #pragma unroll
    for (int mi = 0; mi < 2; ++mi)
        #pragma unroll
        for (int fn = 0; fn < 8; ++fn)
            #pragma unroll
            for (int c = 0; c < 4; ++c) acc[mi][fn][c] = 0.f;

    #pragma unroll
    for (int kb = 0; kb < 4; ++kb) {
        bf16x8 b[8];
        #pragma unroll
        for (int fn = 0; fn < 8; ++fn)
            b[fn] = *reinterpret_cast<const bf16x8*>(
                        &wb[((size_t)(kb * 8 + fn) * 64 + lane) * 8]);
        #pragma unroll
        for (int mi = 0; mi < 2; ++mi) {
            int row = row_base + mi * 16 + l15;
            int rc  = row < M ? row : M - 1;        // clamp; stores guarded
            const f32x4* ap = reinterpret_cast<const f32x4*>(
                                   &x[(size_t)rc * D + kb * 32 + l4 * 8]);
            f32x4 v0 = __builtin_nontemporal_load(ap);
            f32x4 v1 = __builtin_nontemporal_load(ap + 1);
            bf16x8 a;
            a[0]=f2bf(v0[0]); a[1]=f2bf(v0[1]); a[2]=f2bf(v0[2]); a[3]=f2bf(v0[3]);
            a[4]=f2bf(v1[0]); a[5]=f2bf(v1[1]); a[6]=f2bf(v1[2]); a[7]=f2bf(v1[3]);
            #pragma unroll
            for (int fn = 0; fn < 8; ++fn)
                acc[mi][fn] = __builtin_amdgcn_mfma_f32_16x16x32_bf16(
                                  a, b[fn], acc[mi][fn], 0, 0, 0);
        }
    }

    // C/D layout: col = lane&15 (+fn*16), row = (lane>>4)*4 + r (+mi*16)
    #pragma unroll
    for (int mi = 0; mi < 2; ++mi)
        #pragma unroll
        for (int r = 0; r < 4; ++r) {
            int row = row_base + mi * 16 + l4 * 4 + r;
            if (row >= M) continue;
            #pragma unroll
            for (int fn = 0; fn < 8; ++fn)
                y[(size_t)row * D + fn * 16 + l15] = f2bf(acc[mi][fn][r]);
        }
}

// ---------------------------------------------------------------------------
// CSR build: histogram of dst (rank recorded), multi-block scan, bin edges.
// ---------------------------------------------------------------------------
__global__ __launch_bounds__(256) void hist_kernel(
    const int* __restrict__ dst, int* __restrict__ cnt,
    int* __restrict__ rank, int E)
{
    int e = blockIdx.x * 256 + threadIdx.x;
    if (e < E) rank[e] = atomicAdd(&cnt[dst[e]], 1);
}

__global__ __launch_bounds__(256) void scan_part_kernel(
    const int* __restrict__ cnt, int* __restrict__ bsum, int N)
{
    __shared__ int wred[4];
    const int tid  = threadIdx.x;
    const int lane = tid & 63;
    const int wid  = tid >> 6;
    int off = blockIdx.x * SCAN_CH + tid * 16;
    int s = 0;
    #pragma unroll
    for (int i = 0; i < 16; ++i) {
        int idx = off + i;
        if (idx < N) s += cnt[idx];
    }
    #pragma unroll
    for (int d = 32; d >= 1; d >>= 1) s += __shfl_xor(s, d, 64);
    if (lane == 0) wred[wid] = s;
    __syncthreads();
    if (tid == 0) bsum[blockIdx.x] = wred[0] + wred[1] + wred[2] + wred[3];
}

__global__ __launch_bounds__(256) void scan_write_kernel(
    const int* __restrict__ cnt, const int* __restrict__ bsum,
    int* __restrict__ base, int N, int E, int NB)
{
    __shared__ int boff_s;
    __shared__ int wsum[4];
    const int b    = blockIdx.x;
    const int tid  = threadIdx.x;
    const int lane = tid & 63;
    const int wid  = tid >> 6;

    if (wid == 0) {
        int v = (lane < b) ? bsum[lane] : 0;   // NB <= 64
        #pragma unroll
        for (int d = 32; d >= 1; d >>= 1) v += __shfl_xor(v, d, 64);
        if (lane == 0) boff_s = v;
    }
    __syncthreads();

    int off = b * SCAN_CH + tid * 16;
    int v[16];
    int s = 0;
    #pragma unroll
    for (int i = 0; i < 16; ++i) {
        int idx = off + i;
        v[i] = (idx < N) ? cnt[idx] : 0;
        s += v[i];
    }
    int ssum = s;
    #pragma unroll
    for (int d = 1; d < 64; d <<= 1) {
        int t = __shfl_up(ssum, d, 64);
        if (lane >= d) ssum += t;
    }
    if (lane == 63) wsum[wid] = ssum;
    __syncthreads();
    int woff = 0;
    for (int w = 0; w < wid; ++w) woff += wsum[w];

    int run = boff_s + woff + ssum - s;
    #pragma unroll
    for (int i = 0; i < 16; ++i) {
        int idx = off + i;
        if (idx < N) base[idx] = run;
        run += v[i];
    }
    if (b == 0 && tid == 0) base[N] = E;
}

// place edges: no atomics (rank precomputed by hist)
__global__ __launch_bounds__(256) void bin_kernel(
    const int* __restrict__ src, const int* __restrict__ dst,
    const float* __restrict__ ew, const int* __restrict__ base,
    const int* __restrict__ rank, int2* __restrict__ bins, int E)
{
    int e = blockIdx.x * 256 + threadIdx.x;
    if (e >= E) return;
    int p = base[dst[e]] + rank[e];
    bins[p] = make_int2(src[e], __float_as_int(ew[e]));
}

// ---------------------------------------------------------------------------
// Gather-sum from bf16 y: one wave per node, 4 edges in flight.
// out[n] = sum y[src]*w + bias   (out store non-temporal: never re-read)
// ---------------------------------------------------------------------------
__global__ __launch_bounds__(256) void gather_kernel(
    const __bf16* __restrict__ y, const int* __restrict__ base,
    const int2* __restrict__ bins, const float* __restrict__ bias,
    float* __restrict__ out, int N)
{
    int gw   = (blockIdx.x * 256 + threadIdx.x) >> 6;
    int lane = threadIdx.x & 63;
    if (gw >= N) return;

    const unsigned* yb = reinterpret_cast<const unsigned*>(y);  // 2 bf16 / uint
    int b0 = base[gw], b1 = base[gw + 1];
    float accx = 0.f, accy = 0.f;

    for (int i = b0; i < b1; i += 4) {
        int m1 = i + 1 < b1 ? i + 1 : b1 - 1;
        int m2 = i + 2 < b1 ? i + 2 : b1 - 1;
        int m3 = i + 3 < b1 ? i + 3 : b1 - 1;
        int2 e0 = bins[i],  e1 = bins[m1];
        int2 e2 = bins[m2], e3 = bins[m3];
        unsigned p0 = yb[(size_t)e0.x * (D / 2) + lane];
        unsigned p1 = yb[(size_t)e1.x * (D / 2) + lane];
        unsigned p2 = yb[(size_t)e2.x * (D / 2) + lane];
        unsigned p3 = yb[(size_t)e3.x * (D / 2) + lane];
        float w0 = __int_as_float(e0.y);
        float w1 = (i + 1 < b1) ? __int_as_float(e1.y) : 0.f;
        float w2 = (i + 2 < b1) ? __int_as_float(e2.y) : 0.f;
        float w3 = (i + 3 < b1) ? __int_as_float(e3.y) : 0.f;
        accx += __uint_as_float(p0 << 16) * w0;
        accy += __uint_as_float(p0 & 0xFFFF0000u) * w0;
        accx += __uint_as_float(p1 << 16) * w1;
        accy += __uint_as_float(p1 & 0xFFFF0000u) * w1;
        accx += __uint_as_float(p2 << 16) * w2;
        accy += __uint_as_float(p2 & 0xFFFF0000u) * w2;
        accx += __uint_as_float(p3 << 16) * w3;
        accy += __uint_as_float(p3 & 0xFFFF0000u) * w3;
    }

    float2 bv = *reinterpret_cast<const float2*>(&bias[lane * 2]);
    f32x2 o;
    o[0] = accx + bv.x;
    o[1] = accy + bv.y;
    __builtin_nontemporal_store(o, reinterpret_cast<f32x2*>(&out[(size_t)gw * D + lane * 2]));
}

extern "C" void kernel_launch(void* const* d_in, const int* in_sizes, int n_in,
                              void* d_out, int out_size, void* d_ws, size_t ws_size,
                              hipStream_t stream) {
    const float* x   = (const float*)d_in[0];
    const float* ew  = (const float*)d_in[1];
    const int*   src = (const int*)d_in[2];
    const int*   dst = (const int*)d_in[3];
    const float* W   = (const float*)d_in[4];
    const float* b   = (const float*)d_in[5];
    float*       out = (float*)d_out;

    const int E  = in_sizes[2];                 // 640000
    const int M  = out_size / D;                // 100000 nodes
    const int NB = (M + SCAN_CH - 1) / SCAN_CH; // 25 (<=64 required)

    // ws layout: y bf16[M*D] | wb bf16[32*64*8] | bins int2[E] | base[M+1] |
    //            cnt[M] | rank[E] | bsum[NB]
    char* p = (char*)d_ws;
    __bf16* y    = (__bf16*)p;             p += (size_t)M * D * 2;
    __bf16* wb   = (__bf16*)p;             p += (size_t)32 * 64 * 8 * 2;
    int2*   bins = (int2*)p;               p += (size_t)E * 8;
    int*    base = (int*)p;                p += (size_t)(M + 1) * 4;
    int*    cnt  = (int*)p;                p += (size_t)M * 4;
    int*    rank = (int*)p;                p += (size_t)E * 4;
    int*    bsum = (int*)p;

    (void)hipMemsetAsync(cnt, 0, (size_t)M * sizeof(int), stream);

    // W -> fragment-ordered bf16
    pack_w_kernel<<<8, 256, 0, stream>>>(W, wb);

    // y = x @ W^T  (linear commutes with segment_sum)
    gemm_mfma_kernel<<<(M + 127) / 128, 256, 0, stream>>>(x, wb, y, M);

    // CSR build (hist records per-edge rank -> bin needs no atomics)
    hist_kernel<<<(E + 255) / 256, 256, 0, stream>>>(dst, cnt, rank, E);
    scan_part_kernel<<<NB, 256, 0, stream>>>(cnt, bsum, M);
    scan_write_kernel<<<NB, 256, 0, stream>>>(cnt, bsum, base, M, E, NB);
    bin_kernel<<<(E + 255) / 256, 256, 0, stream>>>(src, dst, ew, base, rank, bins, E);

    // out[n] = sum_{e in node n} y[src_e] * w_e + bias
    gather_kernel<<<(M * 64 + 255) / 256, 256, 0, stream>>>(y, base, bins, b, out, M);
}